// Round 16
// baseline (418.508 us; speedup 1.0000x reference)
//
#include <hip/hip_runtime.h>
#include <hip/hip_bf16.h>

// MoE: B=2,S=2048 -> T=4096 tokens, H=1024, F=2048, E=8, TOPK=2
#define TT 4096
#define HH 1024
#define FF 2048
#define EE 8
#define NC32 2048   // EE*FF*HH / (256*32) conv chunks per weight tensor
#define LDSU 32768  // LDS slot stride for down_kernel (bytes)
#define UGSL 65536  // LDS slot stride for up_gate (bytes)

typedef short short8_t __attribute__((ext_vector_type(8)));
typedef float f32x4 __attribute__((ext_vector_type(4)));

__device__ __forceinline__ unsigned short f2b(float f) {
  union { float f; unsigned u; } v; v.f = f;
  return (unsigned short)((v.u + 0x7fffu + ((v.u >> 16) & 1u)) >> 16);  // RNE
}

__device__ __forceinline__ void gload16(const unsigned short* g, void* l) {
  __builtin_amdgcn_global_load_lds(
      (const __attribute__((address_space(1))) void*)g,
      (__attribute__((address_space(3))) void*)l, 16, 0, 0);
}

#define FENCE asm volatile("" ::: "memory")

// Batched-ILP f32->bf16 conv: 8 independent float4 loads in flight per thread.
__device__ __forceinline__ void conv_ilp(const float* __restrict__ src,
                                         unsigned short* __restrict__ dst,
                                         int c, int tid) {
  size_t base = (size_t)c * 8192 + tid * 4;
  float4 v[8];
#pragma unroll
  for (int j = 0; j < 8; ++j)
    v[j] = *reinterpret_cast<const float4*>(src + base + j * 1024);
#pragma unroll
  for (int j = 0; j < 8; ++j) {
    ushort4 b4;
    b4.x = f2b(v[j].x); b4.y = f2b(v[j].y); b4.z = f2b(v[j].z); b4.w = f2b(v[j].w);
    *reinterpret_cast<ushort4*>(dst + base + j * 1024) = b4;
  }
}

// -------- Front: router (atomic-free) + batched-ILP w1/w3[/w2] convs ------------
__global__ __launch_bounds__(256) void front_kernel(
    const float* __restrict__ x, const float* __restrict__ gw,
    const float* __restrict__ w1, const float* __restrict__ w3,
    const float* __restrict__ w2,
    float* __restrict__ out_logits,
    unsigned short* __restrict__ xbf,
    unsigned short* __restrict__ w1bf, unsigned short* __restrict__ w3bf,
    unsigned short* __restrict__ w2bf,
    int* __restrict__ sel01, float2* __restrict__ w01)
{
  int tid = threadIdx.x;
  int b = blockIdx.x;
  if (b >= TT) {
    int cb = b - TT;
    if (cb < NC32)          conv_ilp(w1, w1bf, cb, tid);
    else if (cb < 2 * NC32) conv_ilp(w3, w3bf, cb - NC32, tid);
    else                    conv_ilp(w2, w2bf, cb - 2 * NC32, tid);
    return;
  }
  int t = b;

  __shared__ float xs[HH];
  __shared__ float lg[EE];

  float4 v = reinterpret_cast<const float4*>(x + (size_t)t * HH)[tid];
  xs[tid * 4 + 0] = v.x; xs[tid * 4 + 1] = v.y;
  xs[tid * 4 + 2] = v.z; xs[tid * 4 + 3] = v.w;
  ushort4 b4;
  b4.x = f2b(v.x); b4.y = f2b(v.y); b4.z = f2b(v.z); b4.w = f2b(v.w);
  reinterpret_cast<ushort4*>(xbf + (size_t)t * HH)[tid] = b4;
  __syncthreads();

  int lane = tid & 63, wv = tid >> 6;
  for (int e = wv; e < EE; e += 4) {
    float s = 0.f;
    const float* g = gw + (size_t)e * HH;
#pragma unroll
    for (int j = 0; j < HH / 64; ++j) s += xs[lane + j * 64] * g[lane + j * 64];
#pragma unroll
    for (int off = 32; off > 0; off >>= 1) s += __shfl_down(s, off);
    if (lane == 0) lg[e] = s;
  }
  __syncthreads();

  if (tid < 8) out_logits[(size_t)t * EE + tid] = lg[tid];
  if (tid == 0) {
    float l[EE];
#pragma unroll
    for (int e = 0; e < EE; ++e) l[e] = lg[e];
    int e0 = 0;
#pragma unroll
    for (int e = 1; e < EE; ++e) if (l[e] > l[e0]) e0 = e;
    int e1 = -1;
#pragma unroll
    for (int e = 0; e < EE; ++e) if (e != e0 && (e1 < 0 || l[e] > l[e1])) e1 = e;
    float p1 = expf(l[e1] - l[e0]);
    float w0 = 1.f / (1.f + p1);
    float w1v = p1 * w0;
    sel01[t] = e0 | (e1 << 8);
    w01[t] = make_float2(w0, w1v);
  }
}

// -------- Build: per-expert compacted token lists, atomic-free, deterministic ----
__global__ __launch_bounds__(256) void build_kernel(
    const int* __restrict__ sel01, const float2* __restrict__ w01,
    int* __restrict__ counts, int* __restrict__ tokidx, float* __restrict__ rww)
{
  int e = blockIdx.x;
  int tid = threadIdx.x, lane = tid & 63, wv = tid >> 6;
  __shared__ int wsum[4];
  int base = 0;
  for (int t0 = 0; t0 < TT; t0 += 256) {
    int t = t0 + tid;
    int s = sel01[t];
    int e0 = s & 255, e1 = (s >> 8) & 255;
    bool hit = (e0 == e) || (e1 == e);
    float w = 0.f;
    if (hit) { float2 ww = w01[t]; w = (e0 == e) ? ww.x : ww.y; }
    unsigned long long m = __ballot(hit);
    int wpre = __popcll(m & ((1ull << lane) - 1));
    if (lane == 63) wsum[wv] = wpre + (hit ? 1 : 0);
    __syncthreads();
    int wbase = base;
    for (int q = 0; q < wv; ++q) wbase += wsum[q];
    if (hit) {
      int pos = wbase + wpre;
      tokidx[e * TT + pos] = t;
      rww[e * TT + pos] = w;
    }
    base += wsum[0] + wsum[1] + wsum[2] + wsum[3];
    __syncthreads();
  }
  if (tid == 0) counts[e] = base;
}

// -------- Standalone conv for w2 (fallback when ws too small: after up_gate) ----
__global__ __launch_bounds__(256) void conv_kernel(
    const float* __restrict__ src, unsigned short* __restrict__ dst)
{
  conv_ilp(src, dst, blockIdx.x, threadIdx.x);
}

// -------- Combine: final = slot0 + slot1 (each token has exactly 2 experts) -----
__global__ __launch_bounds__(256) void combine_kernel(
    const float4* __restrict__ s0, const float4* __restrict__ s1,
    float4* __restrict__ out)
{
  size_t i = (size_t)blockIdx.x * 256 + threadIdx.x;
  float4 a = s0[i], b = s1[i];
  float4 r;
  r.x = a.x + b.x; r.y = a.y + b.y; r.z = a.z + b.z; r.w = a.w + b.w;
  out[i] = r;
}

// -------- Up-proj + gate: 512 thr, 256Mx128F dual, BK=64, 4 fine phases/K-tile --
// Slot (bytes): A[0,32768) 256x64, B1[32768,49152) 128x64, B3[49152,65536) 128x64.
// Swizzle: 16B-block index ^= (row&7); pre-swizzled global SOURCE (LDS dest
// linear, per global_load_lds semantics) + swizzled ds_read address.
// Per K-tile (4 phases, 2 barriers each):
//   ph0: reads(k0: A,B1,B3) | MFMA g1.k0
//   ph1: reads(k1)          | MFMA g3.k0   (+ lgkmcnt(0) before closing barrier)
//   ph2: stage half0(T+2)   | MFMA g1.k1   (slot-safe: all reads done at ph1 end)
//   ph3: stage half1(T+2)   | MFMA g3.k1   (+ counted vmcnt(8) once per tile)
__global__ __launch_bounds__(512, 2) void up_gate_kernel(
    const unsigned short* __restrict__ xbf,
    const unsigned short* __restrict__ w1bf, const unsigned short* __restrict__ w3bf,
    const int* __restrict__ counts, const int* __restrict__ tokidx,
    unsigned short* __restrict__ gated)
{
  int e = blockIdx.z;
  int n = counts[e];
  int row0 = blockIdx.y * 256;
  if (row0 >= n) return;
  int fbase = blockIdx.x * 128;

  int pe = 0;
  for (int q = 0; q < e; ++q) pe += (counts[q] + 127) & ~127;
  int prows = (n + 127) & ~127;   // expert's padded row count (gated layout)

  extern __shared__ __align__(16) char lds[];   // 2 * 64 KB

  int tid = threadIdx.x;                  // 0..511
  int lane = tid & 63, wv = tid >> 6;     // wv 0..7
  int sb = (tid & 7) ^ ((tid >> 3) & 7);  // swizzled source 16B-block

  // A sources: 4 passes x 64 rows (rows (tid>>3)+64j), gathered via token list
  const unsigned short* ga[4];
#pragma unroll
  for (int j = 0; j < 4; ++j) {
    int r = min(row0 + (tid >> 3) + 64 * j, n - 1);
    ga[j] = xbf + (size_t)tokidx[e * TT + r] * HH + sb * 8;
  }
  // B sources: 2 passes x 64 rows each (128 F-rows per panel)
  const unsigned short* gb1[2];
  const unsigned short* gb3[2];
#pragma unroll
  for (int j = 0; j < 2; ++j) {
    size_t rw_ = (size_t)e * FF + fbase + (tid >> 3) + 64 * j;
    gb1[j] = w1bf + rw_ * HH + sb * 8;
    gb3[j] = w3bf + rw_ * HH + sb * 8;
  }

  // wave map: 4(M) x 2(F); wave tile 64 rows x 64 F-cols (per gemm)
  int wr = (wv >> 1) * 64;       // 0,64,128,192
  int wcc = (wv & 1) * 64;       // 0,64
  int fr = lane & 15, kq = lane >> 4, l7 = lane & 7;

  f32x4 acc1[4][4], acc3[4][4];  // 128 VGPR total
#pragma unroll
  for (int m = 0; m < 4; ++m)
#pragma unroll
    for (int nn = 0; nn < 4; ++nn) { acc1[m][nn] = (f32x4)0.f; acc3[m][nn] = (f32x4)0.f; }

  short8_t aa0[4], aa1[4], bb1a[4], bb1b[4], bb3a[4], bb3b[4];

#define UG_STAGE_H0(T, SOFF) do {                                        \
    _Pragma("unroll") for (int j = 0; j < 4; ++j)                        \
      gload16(ga[j] + (T) * 64, lds + (SOFF) + j * 8192 + wv * 1024);    \
  } while (0)
#define UG_STAGE_H1(T, SOFF) do {                                        \
    _Pragma("unroll") for (int j = 0; j < 2; ++j) {                      \
      gload16(gb1[j] + (T) * 64, lds + (SOFF) + 32768 + j * 8192 + wv * 1024); \
      gload16(gb3[j] + (T) * 64, lds + (SOFF) + 49152 + j * 8192 + wv * 1024); \
    } } while (0)

#define UG_READS(SOFF, KS, A_, B1_, B3_) do {                                               \
    int bswz = (((KS) * 4 + kq) ^ l7) * 16;                                                 \
    _Pragma("unroll") for (int m = 0; m < 4; ++m)                                           \
      A_[m] = *(const short8_t*)(lds + (SOFF) + (wr + m * 16 + fr) * 128 + bswz);           \
    _Pragma("unroll") for (int nn = 0; nn < 4; ++nn) {                                      \
      B1_[nn] = *(const short8_t*)(lds + (SOFF) + 32768 + (wcc + nn * 16 + fr) * 128 + bswz); \
      B3_[nn] = *(const short8_t*)(lds + (SOFF) + 49152 + (wcc + nn * 16 + fr) * 128 + bswz); \
    } } while (0)

#define UG_MM(ACC, A_, B_) do {                                                             \
    __builtin_amdgcn_s_setprio(1);                                                          \
    _Pragma("unroll") for (int m = 0; m < 4; ++m)                                           \
      _Pragma("unroll") for (int nn = 0; nn < 4; ++nn)                                      \
        ACC[m][nn] = __builtin_amdgcn_mfma_f32_16x16x32_bf16(A_[m], B_[nn], ACC[m][nn], 0, 0, 0); \
    __builtin_amdgcn_s_setprio(0);                                                          \
  } while (0)

#define UG_NT 16
#define UG_TILE(T, SOFF) do {                                            \
    /* ph0: reads k0 | MFMA g1.k0 */                                     \
    UG_READS(SOFF, 0, aa0, bb1a, bb3a);                                  \
    __builtin_amdgcn_s_barrier(); FENCE;                                 \
    UG_MM(acc1, aa0, bb1a);                                              \
    FENCE; __builtin_amdgcn_s_barrier(); FENCE;                          \
    /* ph1: reads k1 | MFMA g3.k0 */                                     \
    UG_READS(SOFF, 1, aa1, bb1b, bb3b);                                  \
    __builtin_amdgcn_s_barrier(); FENCE;                                 \
    UG_MM(acc3, aa0, bb3a);                                              \
    asm volatile("s_waitcnt lgkmcnt(0)" ::: "memory");                   \
    __builtin_amdgcn_sched_barrier(0);                                   \
    __builtin_amdgcn_s_barrier(); FENCE;                                 \
    /* ph2: stage half0(T+2) | MFMA g1.k1 (slot reads all complete) */   \
    if ((T) + 2 < UG_NT) UG_STAGE_H0((T) + 2, SOFF);                     \
    __builtin_amdgcn_s_barrier(); FENCE;                                 \
    UG_MM(acc1, aa1, bb1b);                                              \
    FENCE; __builtin_amdgcn_s_barrier(); FENCE;                          \
    /* ph3: stage half1(T+2) | MFMA g3.k1 | counted vmcnt */             \
    if ((T) + 2 < UG_NT) UG_STAGE_H1((T) + 2, SOFF);                     \
    __builtin_amdgcn_s_barrier(); FENCE;                                 \
    UG_MM(acc3, aa1, bb3b);                                              \
    if ((T) + 1 < UG_NT) asm volatile("s_waitcnt vmcnt(8)" ::: "memory"); \
    else                 asm volatile("s_waitcnt vmcnt(0)" ::: "memory"); \
    __builtin_amdgcn_sched_barrier(0);                                   \
    __builtin_amdgcn_s_barrier(); FENCE;                                 \
  } while (0)

  // prologue: stage tiles 0,1
  UG_STAGE_H0(0, 0);     UG_STAGE_H1(0, 0);
  UG_STAGE_H0(1, UGSL);  UG_STAGE_H1(1, UGSL);
  asm volatile("s_waitcnt vmcnt(8)" ::: "memory");   // tile0 landed; tile1 in flight
  __builtin_amdgcn_s_barrier(); FENCE;

  for (int t2 = 0; t2 < UG_NT; t2 += 2) { UG_TILE(t2, 0); UG_TILE(t2 + 1, UGSL); }
#undef UG_STAGE_H0
#undef UG_STAGE_H1
#undef UG_READS
#undef UG_MM
#undef UG_TILE

  // epilogue: gated = silu(h1)*h3 -> bf16; guard row < prows (gated 128-padded)
  size_t gbase = ((size_t)pe + row0) * FF + fbase;
#pragma unroll
  for (int m = 0; m < 4; ++m) {
#pragma unroll
    for (int nn = 0; nn < 4; ++nn) {
      f32x4 h1v = acc1[m][nn], h3v = acc3[m][nn];
#pragma unroll
      for (int j = 0; j < 4; ++j) {
        int r = wr + m * 16 + kq * 4 + j;
        if (row0 + r < prows) {
          float z = h1v[j];
          float val = (z / (1.f + expf(-z))) * h3v[j];
          int c = wcc + nn * 16 + fr;
          gated[gbase + (size_t)r * FF + c] = f2b(val);
        }
      }
    }
  }
}

// -------- Down-proj: BK=64, 2-slot, software-pipelined reads; slot stores -------
// Slot layout (bytes): A[0,16384) 128x64, B[16384,32768) 128x64.
__global__ __launch_bounds__(256) void down_kernel(
    const unsigned short* __restrict__ gated,
    const unsigned short* __restrict__ w2bf,
    const int* __restrict__ counts, const int* __restrict__ tokidx,
    const float* __restrict__ rww, const int* __restrict__ sel01,
    float* __restrict__ slots)
{
  int e = blockIdx.z;
  int n = counts[e];
  int row0 = blockIdx.y * 128;
  if (row0 >= n) return;
  int hbase = blockIdx.x * 128;
  int valid = min(128, n - row0);

  int pe = 0;
  for (int q = 0; q < e; ++q) pe += (counts[q] + 127) & ~127;

  __shared__ __align__(16) char lds[2 * LDSU];   // 64 KB

  int tid = threadIdx.x;
  int lane = tid & 63, wv = tid >> 6;
  int sb = (tid & 7) ^ ((tid >> 3) & 7);

  const unsigned short* ga[4];
  const unsigned short* gb[4];
#pragma unroll
  for (int j = 0; j < 4; ++j) {
    ga[j] = gated + ((size_t)pe + row0 + (tid >> 3) + 32 * j) * FF + sb * 8;
    gb[j] = w2bf + ((size_t)e * HH + hbase + (tid >> 3) + 32 * j) * FF + sb * 8;
  }

  int wr = (wv >> 1) * 64, wc = (wv & 1) * 64;
  int fr = lane & 15, kq = lane >> 4, l7 = lane & 7;

  f32x4 acc[4][4];
#pragma unroll
  for (int m = 0; m < 4; ++m)
#pragma unroll
    for (int nn = 0; nn < 4; ++nn) acc[m][nn] = (f32x4)0.f;

  short8_t a0[4], bf0[4];
  short8_t a1[4], bf1[4];

#define DN_STAGE(T, SOFF) do {                                                   \
    _Pragma("unroll") for (int j = 0; j < 4; ++j) {                              \
      gload16(ga[j] + (T) * 64, lds + (SOFF) + j * 4096 + wv * 1024);            \
      gload16(gb[j] + (T) * 64, lds + (SOFF) + 16384 + j * 4096 + wv * 1024);    \
    } } while (0)

#define DN_READS(SOFF, KS, A_, B_) do {                                                    \
    int bswz = (((KS) * 4 + kq) ^ l7) * 16;                                                \
    _Pragma("unroll") for (int m = 0; m < 4; ++m)                                          \
      A_[m] = *(const short8_t*)(lds + (SOFF) + (wr + m * 16 + fr) * 128 + bswz);          \
    _Pragma("unroll") for (int nn = 0; nn < 4; ++nn)                                       \
      B_[nn] = *(const short8_t*)(lds + (SOFF) + 16384 + (wc + nn * 16 + fr) * 128 + bswz); \
  } while (0)

#define DN_MFMA(A_, B_) do {                                                               \
    __builtin_amdgcn_s_setprio(1);                                                         \
    _Pragma("unroll") for (int m = 0; m < 4; ++m)                                          \
      _Pragma("unroll") for (int nn = 0; nn < 4; ++nn)                                     \
        acc[m][nn] = __builtin_amdgcn_mfma_f32_16x16x32_bf16(A_[m], B_[nn], acc[m][nn], 0, 0, 0); \
    __builtin_amdgcn_s_setprio(0);                                                         \
  } while (0)

#define DN_WAITS do {                                                  \
    asm volatile("s_waitcnt lgkmcnt(0) vmcnt(0)" ::: "memory");        \
    __builtin_amdgcn_sched_barrier(0);                                 \
    __builtin_amdgcn_s_barrier(); FENCE;                               \
  } while (0)

#define DN_NT 32
  DN_STAGE(0, 0);
  DN_STAGE(1, LDSU);
  asm volatile("s_waitcnt vmcnt(8)" ::: "memory");
  __builtin_amdgcn_s_barrier(); FENCE;
  DN_READS(0, 0, a0, bf0);

  for (int t2 = 0; t2 < DN_NT; t2 += 2) {
    DN_READS(0, 1, a1, bf1);
    DN_MFMA(a0, bf0);
    DN_WAITS;
    if (t2 + 2 < DN_NT) DN_STAGE(t2 + 2, 0);
    DN_READS(LDSU, 0, a0, bf0);
    DN_MFMA(a1, bf1);

    DN_READS(LDSU, 1, a1, bf1);
    DN_MFMA(a0, bf0);
    DN_WAITS;
    if (t2 + 3 < DN_NT) DN_STAGE(t2 + 3, LDSU);
    if (t2 + 2 < DN_NT) DN_READS(0, 0, a0, bf0);
    DN_MFMA(a1, bf1);
  }
#undef DN_STAGE
#undef DN_READS
#undef DN_MFMA
#undef DN_WAITS

  // epilogue: slots[sl][t][h] = rw * out  (plain stores, no atomics)
#pragma unroll
  for (int m = 0; m < 4; ++m) {
    int rbase = wr + m * 16 + (lane >> 4) * 4;
#pragma unroll
    for (int j = 0; j < 4; ++j) {
      int r = rbase + j;
      if (r < valid) {
        int t = tokidx[e * TT + row0 + r];
        float w = rww[e * TT + row0 + r];
        int sl = ((sel01[t] & 255) == e) ? 0 : 1;
        float* dst = slots + (size_t)sl * TT * HH + (size_t)t * HH;
#pragma unroll
        for (int nn = 0; nn < 4; ++nn) {
          int c = hbase + wc + nn * 16 + fr;
          dst[c] = w * acc[m][nn][j];
        }
      }
    }
  }
}

extern "C" void kernel_launch(void* const* d_in, const int* in_sizes, int n_in,
                              void* d_out, int out_size, void* d_ws, size_t ws_size,
                              hipStream_t stream) {
  const float* x  = (const float*)d_in[0];   // [T, H]
  const float* gw = (const float*)d_in[1];   // [E, H]
  const float* w1 = (const float*)d_in[2];   // [E, F, H]
  const float* w2 = (const float*)d_in[3];   // [E, H, F]
  const float* w3 = (const float*)d_in[4];   // [E, F, H]

  float* final_out  = (float*)d_out;                       // [T, H]
  float* out_logits = final_out + (size_t)TT * HH;         // [T, E]

  char* ws = (char*)d_ws;
  int*    counts = (int*)(ws + 0);                            // 64 B
  int*    sel01  = (int*)(ws + 1024);                         // 16384
  float2* w01    = (float2*)(ws + 20480);                     // 32768
  int*    tokidx = (int*)(ws + 53248);                        // 131072
  float*  rww    = (float*)(ws + 184320);                     // 131072
  unsigned short* xbf   = (unsigned short*)(ws + 315392);     // 8388608
  unsigned short* w1bf  = (unsigned short*)(ws + 8704000);    // 33554432
  unsigned short* w3bf  = (unsigned short*)(ws + 42258432);   // 33554432
  unsigned short* gated = (unsigned short*)(ws + 75812864);   // 37748736
  const size_t base_end = 113561600;
  bool big = ws_size >= base_end + 33554432;                  // +32MB for w2bf
  unsigned short* w2bf = big ? (unsigned short*)(ws + base_end) : w1bf;
  // down-proj output slots [2][T][H] f32 = 32MB, aliasing w3bf (dead after up_gate)
  float* slots = (float*)w3bf;

  int nconvblk = (big ? 3 : 2) * NC32;
  front_kernel<<<TT + nconvblk, 256, 0, stream>>>(
      x, gw, w1, w3, w2, out_logits, xbf, w1bf, w3bf, w2bf, sel01, w01);
  build_kernel<<<EE, 256, 0, stream>>>(sel01, w01, counts, tokidx, rww);
  up_gate_kernel<<<dim3(FF / 128, TT / 256, EE), 512, 2 * UGSL, stream>>>(
      xbf, w1bf, w3bf, counts, tokidx, gated);
  if (!big) conv_kernel<<<NC32, 256, 0, stream>>>(w2, w1bf);
  down_kernel<<<dim3(HH / 128, TT / 128, EE), 256, 0, stream>>>(
      gated, w2bf, counts, tokidx, rww, sel01, slots);
  combine_kernel<<<TT * HH / 1024, 256, 0, stream>>>(
      (const float4*)slots, (const float4*)(slots + (size_t)TT * HH),
      (float4*)final_out);
}

// Round 17
// 248.884 us; speedup vs baseline: 1.6815x; 1.6815x over previous
//
#include <hip/hip_runtime.h>
#include <hip/hip_bf16.h>

// MoE: B=2,S=2048 -> T=4096 tokens, H=1024, F=2048, E=8, TOPK=2
#define TT 4096
#define HH 1024
#define FF 2048
#define EE 8
#define NC32 2048   // EE*FF*HH / (256*32) conv chunks per weight tensor
#define LDSU 32768  // LDS slot stride (bytes)

typedef short short8_t __attribute__((ext_vector_type(8)));
typedef float f32x4 __attribute__((ext_vector_type(4)));

__device__ __forceinline__ unsigned short f2b(float f) {
  union { float f; unsigned u; } v; v.f = f;
  return (unsigned short)((v.u + 0x7fffu + ((v.u >> 16) & 1u)) >> 16);  // RNE
}

__device__ __forceinline__ void gload16(const unsigned short* g, void* l) {
  __builtin_amdgcn_global_load_lds(
      (const __attribute__((address_space(1))) void*)g,
      (__attribute__((address_space(3))) void*)l, 16, 0, 0);
}

#define FENCE asm volatile("" ::: "memory")

// Batched-ILP f32->bf16 conv: 8 independent float4 loads in flight per thread.
__device__ __forceinline__ void conv_ilp(const float* __restrict__ src,
                                         unsigned short* __restrict__ dst,
                                         int c, int tid) {
  size_t base = (size_t)c * 8192 + tid * 4;
  float4 v[8];
#pragma unroll
  for (int j = 0; j < 8; ++j)
    v[j] = *reinterpret_cast<const float4*>(src + base + j * 1024);
#pragma unroll
  for (int j = 0; j < 8; ++j) {
    ushort4 b4;
    b4.x = f2b(v[j].x); b4.y = f2b(v[j].y); b4.z = f2b(v[j].z); b4.w = f2b(v[j].w);
    *reinterpret_cast<ushort4*>(dst + base + j * 1024) = b4;
  }
}

// -------- Front: router (atomic-free) + batched-ILP w1/w3[/w2] convs ------------
__global__ __launch_bounds__(256) void front_kernel(
    const float* __restrict__ x, const float* __restrict__ gw,
    const float* __restrict__ w1, const float* __restrict__ w3,
    const float* __restrict__ w2,
    float* __restrict__ out_logits,
    unsigned short* __restrict__ xbf,
    unsigned short* __restrict__ w1bf, unsigned short* __restrict__ w3bf,
    unsigned short* __restrict__ w2bf,
    int* __restrict__ sel01, float2* __restrict__ w01)
{
  int tid = threadIdx.x;
  int b = blockIdx.x;
  if (b >= TT) {
    int cb = b - TT;
    if (cb < NC32)          conv_ilp(w1, w1bf, cb, tid);
    else if (cb < 2 * NC32) conv_ilp(w3, w3bf, cb - NC32, tid);
    else                    conv_ilp(w2, w2bf, cb - 2 * NC32, tid);
    return;
  }
  int t = b;

  __shared__ float xs[HH];
  __shared__ float lg[EE];

  float4 v = reinterpret_cast<const float4*>(x + (size_t)t * HH)[tid];
  xs[tid * 4 + 0] = v.x; xs[tid * 4 + 1] = v.y;
  xs[tid * 4 + 2] = v.z; xs[tid * 4 + 3] = v.w;
  ushort4 b4;
  b4.x = f2b(v.x); b4.y = f2b(v.y); b4.z = f2b(v.z); b4.w = f2b(v.w);
  reinterpret_cast<ushort4*>(xbf + (size_t)t * HH)[tid] = b4;
  __syncthreads();

  int lane = tid & 63, wv = tid >> 6;
  for (int e = wv; e < EE; e += 4) {
    float s = 0.f;
    const float* g = gw + (size_t)e * HH;
#pragma unroll
    for (int j = 0; j < HH / 64; ++j) s += xs[lane + j * 64] * g[lane + j * 64];
#pragma unroll
    for (int off = 32; off > 0; off >>= 1) s += __shfl_down(s, off);
    if (lane == 0) lg[e] = s;
  }
  __syncthreads();

  if (tid < 8) out_logits[(size_t)t * EE + tid] = lg[tid];
  if (tid == 0) {
    float l[EE];
#pragma unroll
    for (int e = 0; e < EE; ++e) l[e] = lg[e];
    int e0 = 0;
#pragma unroll
    for (int e = 1; e < EE; ++e) if (l[e] > l[e0]) e0 = e;
    int e1 = -1;
#pragma unroll
    for (int e = 0; e < EE; ++e) if (e != e0 && (e1 < 0 || l[e] > l[e1])) e1 = e;
    float p1 = expf(l[e1] - l[e0]);
    float w0 = 1.f / (1.f + p1);
    float w1v = p1 * w0;
    sel01[t] = e0 | (e1 << 8);
    w01[t] = make_float2(w0, w1v);
  }
}

// -------- Build: per-expert compacted token lists, atomic-free, deterministic ----
__global__ __launch_bounds__(256) void build_kernel(
    const int* __restrict__ sel01, const float2* __restrict__ w01,
    int* __restrict__ counts, int* __restrict__ tokidx, float* __restrict__ rww)
{
  int e = blockIdx.x;
  int tid = threadIdx.x, lane = tid & 63, wv = tid >> 6;
  __shared__ int wsum[4];
  int base = 0;
  for (int t0 = 0; t0 < TT; t0 += 256) {
    int t = t0 + tid;
    int s = sel01[t];
    int e0 = s & 255, e1 = (s >> 8) & 255;
    bool hit = (e0 == e) || (e1 == e);
    float w = 0.f;
    if (hit) { float2 ww = w01[t]; w = (e0 == e) ? ww.x : ww.y; }
    unsigned long long m = __ballot(hit);
    int wpre = __popcll(m & ((1ull << lane) - 1));
    if (lane == 63) wsum[wv] = wpre + (hit ? 1 : 0);
    __syncthreads();
    int wbase = base;
    for (int q = 0; q < wv; ++q) wbase += wsum[q];
    if (hit) {
      int pos = wbase + wpre;
      tokidx[e * TT + pos] = t;
      rww[e * TT + pos] = w;
    }
    base += wsum[0] + wsum[1] + wsum[2] + wsum[3];
    __syncthreads();
  }
  if (tid == 0) counts[e] = base;
}

// -------- Standalone conv for w2 (fallback when ws too small: after up_gate) ----
__global__ __launch_bounds__(256) void conv_kernel(
    const float* __restrict__ src, unsigned short* __restrict__ dst)
{
  conv_ilp(src, dst, blockIdx.x, threadIdx.x);
}

// -------- Combine: final = slot0 + slot1 (each token has exactly 2 experts) -----
__global__ __launch_bounds__(256) void combine_kernel(
    const float4* __restrict__ s0, const float4* __restrict__ s1,
    float4* __restrict__ out)
{
  size_t i = (size_t)blockIdx.x * 256 + threadIdx.x;
  float4 a = s0[i], b = s1[i];
  float4 r;
  r.x = a.x + b.x; r.y = a.y + b.y; r.z = a.z + b.z; r.w = a.w + b.w;
  out[i] = r;
}

// -------- Up-proj + gate: BK=64, 2-slot, software-pipelined reads ---------------
// Slot layout (bytes): A[0,16384) 128x64, B1[16384,24576) 64x64, B3[24576,32768).
// Swizzle: 16B-block index ^= (row & 7); pre-swizzled global SOURCE at stage time
// (LDS dest linear) + swizzled ds_read address.
// Schedule per K-tile: {reads(s1) | MFMA(s0) | lgkm0+vmcnt0 | barrier |
//                       stage(T+2) | reads(T+1,s0) | MFMA(s1)}  — 1 barrier/tile.
__global__ __launch_bounds__(256) void up_gate_kernel(
    const unsigned short* __restrict__ xbf,
    const unsigned short* __restrict__ w1bf, const unsigned short* __restrict__ w3bf,
    const int* __restrict__ counts, const int* __restrict__ tokidx,
    unsigned short* __restrict__ gated)
{
  int e = blockIdx.z;
  int n = counts[e];
  int row0 = blockIdx.y * 128;
  if (row0 >= n) return;
  int fbase = blockIdx.x * 64;

  int pe = 0;
  for (int q = 0; q < e; ++q) pe += (counts[q] + 127) & ~127;

  __shared__ __align__(16) char lds[2 * LDSU];   // 64 KB

  int tid = threadIdx.x;
  int lane = tid & 63, wv = tid >> 6;
  int sb = (tid & 7) ^ ((tid >> 3) & 7);   // swizzled source 16B-block

  const unsigned short* ga[4];
#pragma unroll
  for (int j = 0; j < 4; ++j) {
    int r = min(row0 + (tid >> 3) + 32 * j, n - 1);
    ga[j] = xbf + (size_t)tokidx[e * TT + r] * HH + sb * 8;
  }
  const unsigned short* gb1[2];
  const unsigned short* gb3[2];
#pragma unroll
  for (int j = 0; j < 2; ++j) {
    size_t rw_ = (size_t)e * FF + fbase + (tid >> 3) + 32 * j;
    gb1[j] = w1bf + rw_ * HH + sb * 8;
    gb3[j] = w3bf + rw_ * HH + sb * 8;
  }

  int wr = (wv >> 1) * 64, wc = (wv & 1) * 32;
  int fr = lane & 15, kq = lane >> 4, l7 = lane & 7;

  f32x4 acc1[4][2], acc3[4][2];
#pragma unroll
  for (int m = 0; m < 4; ++m)
#pragma unroll
    for (int nn = 0; nn < 2; ++nn) { acc1[m][nn] = (f32x4)0.f; acc3[m][nn] = (f32x4)0.f; }

  // double-buffered fragment registers
  short8_t a0[4], b10[2], b30[2];
  short8_t a1[4], b11[2], b31[2];

#define UG_STAGE(T, SOFF) do {                                                     \
    _Pragma("unroll") for (int j = 0; j < 4; ++j)                                  \
      gload16(ga[j] + (T) * 64, lds + (SOFF) + j * 4096 + wv * 1024);              \
    _Pragma("unroll") for (int j = 0; j < 2; ++j) {                                \
      gload16(gb1[j] + (T) * 64, lds + (SOFF) + 16384 + j * 4096 + wv * 1024);     \
      gload16(gb3[j] + (T) * 64, lds + (SOFF) + 24576 + j * 4096 + wv * 1024);     \
    } } while (0)

#define UG_READS(SOFF, KS, A_, B1_, B3_) do {                                               \
    int bswz = (((KS) * 4 + kq) ^ l7) * 16;                                                 \
    _Pragma("unroll") for (int m = 0; m < 4; ++m)                                           \
      A_[m] = *(const short8_t*)(lds + (SOFF) + (wr + m * 16 + fr) * 128 + bswz);           \
    _Pragma("unroll") for (int nn = 0; nn < 2; ++nn) {                                      \
      B1_[nn] = *(const short8_t*)(lds + (SOFF) + 16384 + (wc + nn * 16 + fr) * 128 + bswz); \
      B3_[nn] = *(const short8_t*)(lds + (SOFF) + 24576 + (wc + nn * 16 + fr) * 128 + bswz); \
    } } while (0)

#define UG_MFMA(A_, B1_, B3_) do {                                                          \
    __builtin_amdgcn_s_setprio(1);                                                          \
    _Pragma("unroll") for (int m = 0; m < 4; ++m)                                           \
      _Pragma("unroll") for (int nn = 0; nn < 2; ++nn) {                                    \
        acc1[m][nn] = __builtin_amdgcn_mfma_f32_16x16x32_bf16(A_[m], B1_[nn], acc1[m][nn], 0, 0, 0); \
        acc3[m][nn] = __builtin_amdgcn_mfma_f32_16x16x32_bf16(A_[m], B3_[nn], acc3[m][nn], 0, 0, 0); \
      }                                                                                     \
    __builtin_amdgcn_s_setprio(0);                                                          \
  } while (0)

#define UG_WAITS do {                                                  \
    asm volatile("s_waitcnt lgkmcnt(0) vmcnt(0)" ::: "memory");        \
    __builtin_amdgcn_sched_barrier(0);                                 \
    __builtin_amdgcn_s_barrier(); FENCE;                               \
  } while (0)

#define UG_NT 16
  // prologue
  UG_STAGE(0, 0);
  UG_STAGE(1, LDSU);
  asm volatile("s_waitcnt vmcnt(8)" ::: "memory");   // tile0 staged; tile1 in flight
  __builtin_amdgcn_s_barrier(); FENCE;
  UG_READS(0, 0, a0, b10, b30);                      // tile0 sub0

  for (int t2 = 0; t2 < UG_NT; t2 += 2) {
    // tile t2 (cur slot0, next slot1)
    UG_READS(0, 1, a1, b11, b31);
    UG_MFMA(a0, b10, b30);
    UG_WAITS;                                        // slot0 reads done everywhere; stage(t2+1) landed
    if (t2 + 2 < UG_NT) UG_STAGE(t2 + 2, 0);
    UG_READS(LDSU, 0, a0, b10, b30);                 // tile t2+1 sub0
    UG_MFMA(a1, b11, b31);
    // tile t2+1 (cur slot1, next slot0)
    UG_READS(LDSU, 1, a1, b11, b31);
    UG_MFMA(a0, b10, b30);
    UG_WAITS;                                        // slot1 reads done; stage(t2+2) landed
    if (t2 + 3 < UG_NT) UG_STAGE(t2 + 3, LDSU);
    if (t2 + 2 < UG_NT) UG_READS(0, 0, a0, b10, b30); // tile t2+2 sub0
    UG_MFMA(a1, b11, b31);
  }
#undef UG_STAGE
#undef UG_READS
#undef UG_MFMA
#undef UG_WAITS

  // epilogue: gated = silu(h1)*h3 -> bf16
  size_t gbase = ((size_t)pe + row0) * FF + fbase;
#pragma unroll
  for (int m = 0; m < 4; ++m) {
#pragma unroll
    for (int nn = 0; nn < 2; ++nn) {
      f32x4 h1v = acc1[m][nn], h3v = acc3[m][nn];
#pragma unroll
      for (int j = 0; j < 4; ++j) {
        float z = h1v[j];
        float val = (z / (1.f + expf(-z))) * h3v[j];
        int r = wr + m * 16 + (lane >> 4) * 4 + j;
        int c = wc + nn * 16 + fr;
        gated[gbase + (size_t)r * FF + c] = f2b(val);
      }
    }
  }
}

// -------- Down-proj: BK=64, 2-slot, software-pipelined reads; slot stores -------
// Slot layout (bytes): A[0,16384) 128x64, B[16384,32768) 128x64.
__global__ __launch_bounds__(256) void down_kernel(
    const unsigned short* __restrict__ gated,
    const unsigned short* __restrict__ w2bf,
    const int* __restrict__ counts, const int* __restrict__ tokidx,
    const float* __restrict__ rww, const int* __restrict__ sel01,
    float* __restrict__ slots)
{
  int e = blockIdx.z;
  int n = counts[e];
  int row0 = blockIdx.y * 128;
  if (row0 >= n) return;
  int hbase = blockIdx.x * 128;
  int valid = min(128, n - row0);

  int pe = 0;
  for (int q = 0; q < e; ++q) pe += (counts[q] + 127) & ~127;

  __shared__ __align__(16) char lds[2 * LDSU];   // 64 KB

  int tid = threadIdx.x;
  int lane = tid & 63, wv = tid >> 6;
  int sb = (tid & 7) ^ ((tid >> 3) & 7);

  const unsigned short* ga[4];
  const unsigned short* gb[4];
#pragma unroll
  for (int j = 0; j < 4; ++j) {
    ga[j] = gated + ((size_t)pe + row0 + (tid >> 3) + 32 * j) * FF + sb * 8;
    gb[j] = w2bf + ((size_t)e * HH + hbase + (tid >> 3) + 32 * j) * FF + sb * 8;
  }

  int wr = (wv >> 1) * 64, wc = (wv & 1) * 64;
  int fr = lane & 15, kq = lane >> 4, l7 = lane & 7;

  f32x4 acc[4][4];
#pragma unroll
  for (int m = 0; m < 4; ++m)
#pragma unroll
    for (int nn = 0; nn < 4; ++nn) acc[m][nn] = (f32x4)0.f;

  short8_t a0[4], bf0[4];
  short8_t a1[4], bf1[4];

#define DN_STAGE(T, SOFF) do {                                                   \
    _Pragma("unroll") for (int j = 0; j < 4; ++j) {                              \
      gload16(ga[j] + (T) * 64, lds + (SOFF) + j * 4096 + wv * 1024);            \
      gload16(gb[j] + (T) * 64, lds + (SOFF) + 16384 + j * 4096 + wv * 1024);    \
    } } while (0)

#define DN_READS(SOFF, KS, A_, B_) do {                                                    \
    int bswz = (((KS) * 4 + kq) ^ l7) * 16;                                                \
    _Pragma("unroll") for (int m = 0; m < 4; ++m)                                          \
      A_[m] = *(const short8_t*)(lds + (SOFF) + (wr + m * 16 + fr) * 128 + bswz);          \
    _Pragma("unroll") for (int nn = 0; nn < 4; ++nn)                                       \
      B_[nn] = *(const short8_t*)(lds + (SOFF) + 16384 + (wc + nn * 16 + fr) * 128 + bswz); \
  } while (0)

#define DN_MFMA(A_, B_) do {                                                               \
    __builtin_amdgcn_s_setprio(1);                                                         \
    _Pragma("unroll") for (int m = 0; m < 4; ++m)                                          \
      _Pragma("unroll") for (int nn = 0; nn < 4; ++nn)                                     \
        acc[m][nn] = __builtin_amdgcn_mfma_f32_16x16x32_bf16(A_[m], B_[nn], acc[m][nn], 0, 0, 0); \
    __builtin_amdgcn_s_setprio(0);                                                         \
  } while (0)

#define DN_WAITS do {                                                  \
    asm volatile("s_waitcnt lgkmcnt(0) vmcnt(0)" ::: "memory");        \
    __builtin_amdgcn_sched_barrier(0);                                 \
    __builtin_amdgcn_s_barrier(); FENCE;                               \
  } while (0)

#define DN_NT 32
  DN_STAGE(0, 0);
  DN_STAGE(1, LDSU);
  asm volatile("s_waitcnt vmcnt(8)" ::: "memory");
  __builtin_amdgcn_s_barrier(); FENCE;
  DN_READS(0, 0, a0, bf0);

  for (int t2 = 0; t2 < DN_NT; t2 += 2) {
    DN_READS(0, 1, a1, bf1);
    DN_MFMA(a0, bf0);
    DN_WAITS;
    if (t2 + 2 < DN_NT) DN_STAGE(t2 + 2, 0);
    DN_READS(LDSU, 0, a0, bf0);
    DN_MFMA(a1, bf1);

    DN_READS(LDSU, 1, a1, bf1);
    DN_MFMA(a0, bf0);
    DN_WAITS;
    if (t2 + 3 < DN_NT) DN_STAGE(t2 + 3, LDSU);
    if (t2 + 2 < DN_NT) DN_READS(0, 0, a0, bf0);
    DN_MFMA(a1, bf1);
  }
#undef DN_STAGE
#undef DN_READS
#undef DN_MFMA
#undef DN_WAITS

  // epilogue: slots[sl][t][h] = rw * out  (plain stores, no atomics)
#pragma unroll
  for (int m = 0; m < 4; ++m) {
    int rbase = wr + m * 16 + (lane >> 4) * 4;
#pragma unroll
    for (int j = 0; j < 4; ++j) {
      int r = rbase + j;
      if (r < valid) {
        int t = tokidx[e * TT + row0 + r];
        float w = rww[e * TT + row0 + r];
        int sl = ((sel01[t] & 255) == e) ? 0 : 1;
        float* dst = slots + (size_t)sl * TT * HH + (size_t)t * HH;
#pragma unroll
        for (int nn = 0; nn < 4; ++nn) {
          int c = hbase + wc + nn * 16 + fr;
          dst[c] = w * acc[m][nn][j];
        }
      }
    }
  }
}

extern "C" void kernel_launch(void* const* d_in, const int* in_sizes, int n_in,
                              void* d_out, int out_size, void* d_ws, size_t ws_size,
                              hipStream_t stream) {
  const float* x  = (const float*)d_in[0];   // [T, H]
  const float* gw = (const float*)d_in[1];   // [E, H]
  const float* w1 = (const float*)d_in[2];   // [E, F, H]
  const float* w2 = (const float*)d_in[3];   // [E, H, F]
  const float* w3 = (const float*)d_in[4];   // [E, F, H]

  float* final_out  = (float*)d_out;                       // [T, H]
  float* out_logits = final_out + (size_t)TT * HH;         // [T, E]

  char* ws = (char*)d_ws;
  int*    counts = (int*)(ws + 0);                            // 64 B
  int*    sel01  = (int*)(ws + 1024);                         // 16384
  float2* w01    = (float2*)(ws + 20480);                     // 32768
  int*    tokidx = (int*)(ws + 53248);                        // 131072
  float*  rww    = (float*)(ws + 184320);                     // 131072
  unsigned short* xbf   = (unsigned short*)(ws + 315392);     // 8388608
  unsigned short* w1bf  = (unsigned short*)(ws + 8704000);    // 33554432
  unsigned short* w3bf  = (unsigned short*)(ws + 42258432);   // 33554432
  unsigned short* gated = (unsigned short*)(ws + 75812864);   // 37748736
  const size_t base_end = 113561600;
  bool big = ws_size >= base_end + 33554432;                  // +32MB for w2bf
  unsigned short* w2bf = big ? (unsigned short*)(ws + base_end) : w1bf;
  // down-proj output slots [2][T][H] f32 = 32MB, aliasing w3bf (dead after up_gate)
  float* slots = (float*)w3bf;

  int nconvblk = (big ? 3 : 2) * NC32;
  front_kernel<<<TT + nconvblk, 256, 0, stream>>>(
      x, gw, w1, w3, w2, out_logits, xbf, w1bf, w3bf, w2bf, sel01, w01);
  build_kernel<<<EE, 256, 0, stream>>>(sel01, w01, counts, tokidx, rww);
  up_gate_kernel<<<dim3(FF / 64, TT / 128, EE), 256, 0, stream>>>(
      xbf, w1bf, w3bf, counts, tokidx, gated);
  if (!big) conv_kernel<<<NC32, 256, 0, stream>>>(w2, w1bf);
  down_kernel<<<dim3(HH / 128, TT / 128, EE), 256, 0, stream>>>(
      gated, w2bf, counts, tokidx, rww, sel01, slots);
  combine_kernel<<<TT * HH / 1024, 256, 0, stream>>>(
      (const float4*)slots, (const float4*)(slots + (size_t)TT * HH),
      (float4*)final_out);
}